// Round 5
// baseline (132.714 us; speedup 1.0000x reference)
//
#include <hip/hip_runtime.h>
#include <hip/hip_bf16.h>

using bf16x8 = __attribute__((ext_vector_type(8))) __bf16;
using f32x4  = __attribute__((ext_vector_type(4))) float;
typedef unsigned int u32;

#define DFEAT 512
#define SLOTS 64
#define FS 128          // aggregate feature-slice: N*4 lines = 2.56 MB < 4 MB L2/XCD
#define NSLICE 4

static __device__ __forceinline__ unsigned short f2bfbits(float f) {
    union { float f; unsigned int u; } v; v.f = f;
    unsigned int u = v.u;
    unsigned int r = (u + 0x7fffu + ((u >> 16) & 1u)) >> 16;
    return (unsigned short)r;
}

// async global->LDS, 16B per lane: LDS dest = wave-uniform base + lane*16
static __device__ __forceinline__ void gload16(const unsigned short* g, unsigned short* l) {
    __builtin_amdgcn_global_load_lds(
        (const __attribute__((address_space(1))) u32*)g,
        (__attribute__((address_space(3))) u32*)l, 16, 0, 0);
}

// -------- fused: fp32->bf16 convert (X,W) + slot-scatter edges by dst --------
__global__ __launch_bounds__(256) void cvt_scatter_kernel(
    const float* __restrict__ x, const float* __restrict__ w,
    unsigned short* __restrict__ Xb, unsigned short* __restrict__ Wb,
    const int* __restrict__ srcv, const int* __restrict__ dstv,
    int* __restrict__ cur, int* __restrict__ slot,
    int nx4, int ntot4, int E, int T)
{
    int i = blockIdx.x * 256 + threadIdx.x;
    if (i < ntot4) {
        const float* in = (i < nx4) ? x : w;
        unsigned short* o = (i < nx4) ? Xb : Wb;
        int j = (i < nx4) ? i : i - nx4;
        float4 v = ((const float4*)in)[j];
        ushort4 u;
        u.x = f2bfbits(v.x); u.y = f2bfbits(v.y);
        u.z = f2bfbits(v.z); u.w = f2bfbits(v.w);
        ((ushort4*)o)[j] = u;
    }
    if (i < T) {
        int s, d;
        if (i < E) { s = srcv[i]; d = dstv[i]; }
        else       { s = d = i - E; }          // self-loops appended
        int pos = atomicAdd(&cur[d], 1);
        if (pos < SLOTS) slot[(size_t)d * SLOTS + pos] = s;
    }
}

// -------- GEMM: H[m][n] = sum_k X[m][k]*W[n][k], m97-style LDS double-buffer ----
// (unchanged from round 4 -- this round's single variable is the aggregate)
__global__ __launch_bounds__(256, 3) void gemm_h_kernel(
    const unsigned short* __restrict__ X, const unsigned short* __restrict__ Wm,
    const float* __restrict__ avs, const float* __restrict__ avd,
    unsigned short* __restrict__ H, float* __restrict__ es, float* __restrict__ ed,
    int N)
{
    __shared__ __align__(16) unsigned short Asm[2][128 * 64];  // 16 KiB/buf
    __shared__ __align__(16) unsigned short Bsm[2][64 * 64];   //  8 KiB/buf

    int L = blockIdx.x;
    int xcd = L & 7;
    int q   = L >> 3;
    int rpan = (q >> 3) * 8 + xcd;             // row panel (128 rows)
    int cpan = q & 7;                          // col panel (64 cols)
    int rowPanels = (N + 127) >> 7;
    if (rpan >= rowPanels) return;
    int bm = rpan * 128;
    int bn = cpan * 64;

    int tid  = threadIdx.x;
    int wave = tid >> 6;
    int lane = tid & 63;
    int l15  = lane & 15;
    int quad = lane >> 4;

    int srow   = lane >> 3;                    // 0..7
    int schunk = (lane & 7) ^ srow;            // inverse-swizzled source chunk
    const unsigned short* gA0;
    const unsigned short* gA1;
    const unsigned short* gA2;
    const unsigned short* gA3;
    {
        int r0 = bm + wave * 32 +  0 + srow; r0 = r0 < N ? r0 : N - 1;
        int r1 = bm + wave * 32 +  8 + srow; r1 = r1 < N ? r1 : N - 1;
        int r2 = bm + wave * 32 + 16 + srow; r2 = r2 < N ? r2 : N - 1;
        int r3 = bm + wave * 32 + 24 + srow; r3 = r3 < N ? r3 : N - 1;
        gA0 = X + (size_t)r0 * DFEAT + schunk * 8;
        gA1 = X + (size_t)r1 * DFEAT + schunk * 8;
        gA2 = X + (size_t)r2 * DFEAT + schunk * 8;
        gA3 = X + (size_t)r3 * DFEAT + schunk * 8;
    }
    const unsigned short* gB0 = Wm + (size_t)(bn + wave * 16 + srow) * DFEAT + schunk * 8;
    const unsigned short* gB1 = gB0 + (size_t)8 * DFEAT;

    auto stage = [&](int buf, int s) {
        int ko = s * 64;                       // k-offset in elements
        gload16(gA0 + ko, &Asm[buf][(wave * 32 +  0) * 64]);
        gload16(gA1 + ko, &Asm[buf][(wave * 32 +  8) * 64]);
        gload16(gA2 + ko, &Asm[buf][(wave * 32 + 16) * 64]);
        gload16(gA3 + ko, &Asm[buf][(wave * 32 + 24) * 64]);
        gload16(gB0 + ko, &Bsm[buf][(wave * 16 + 0) * 64]);
        gload16(gB1 + ko, &Bsm[buf][(wave * 16 + 8) * 64]);
    };

    f32x4 acc[2][4] = {};
    int xa = l15 & 7;                          // row&7 for this lane's A/B rows
    int aoff0 = (wave * 32 +  0 + l15) * 128;  // A row byte offsets
    int aoff1 = (wave * 32 + 16 + l15) * 128;

    auto compute = [&](int buf) {
        const char* Ab = (const char*)&Asm[buf][0];
        const char* Bb = (const char*)&Bsm[buf][0];
        #pragma unroll
        for (int ks = 0; ks < 2; ++ks) {
            int cb = ((ks * 4 + quad) ^ xa) * 16;   // swizzled chunk byte
            bf16x8 a0 = *(const bf16x8*)(Ab + aoff0 + cb);
            bf16x8 a1 = *(const bf16x8*)(Ab + aoff1 + cb);
            bf16x8 b0 = *(const bf16x8*)(Bb + (0 * 16 + l15) * 128 + cb);
            bf16x8 b1 = *(const bf16x8*)(Bb + (1 * 16 + l15) * 128 + cb);
            bf16x8 b2 = *(const bf16x8*)(Bb + (2 * 16 + l15) * 128 + cb);
            bf16x8 b3 = *(const bf16x8*)(Bb + (3 * 16 + l15) * 128 + cb);
            acc[0][0] = __builtin_amdgcn_mfma_f32_16x16x32_bf16(a0, b0, acc[0][0], 0, 0, 0);
            acc[1][0] = __builtin_amdgcn_mfma_f32_16x16x32_bf16(a1, b0, acc[1][0], 0, 0, 0);
            acc[0][1] = __builtin_amdgcn_mfma_f32_16x16x32_bf16(a0, b1, acc[0][1], 0, 0, 0);
            acc[1][1] = __builtin_amdgcn_mfma_f32_16x16x32_bf16(a1, b1, acc[1][1], 0, 0, 0);
            acc[0][2] = __builtin_amdgcn_mfma_f32_16x16x32_bf16(a0, b2, acc[0][2], 0, 0, 0);
            acc[1][2] = __builtin_amdgcn_mfma_f32_16x16x32_bf16(a1, b2, acc[1][2], 0, 0, 0);
            acc[0][3] = __builtin_amdgcn_mfma_f32_16x16x32_bf16(a0, b3, acc[0][3], 0, 0, 0);
            acc[1][3] = __builtin_amdgcn_mfma_f32_16x16x32_bf16(a1, b3, acc[1][3], 0, 0, 0);
        }
    };

    stage(0, 0);
    __syncthreads();                           // drains vmcnt(0) before first read
    int buf = 0;
    for (int s = 0; s < 7; ++s) {
        stage(buf ^ 1, s + 1);                 // issue next-step loads (async)
        compute(buf);                          // ds_read + 16 MFMA on current
        __syncthreads();                       // drain loads + reads, flip
        buf ^= 1;
    }
    compute(buf);                              // last step, no prefetch

    // ---- epilogue: H store + fused e_src/e_dst partial dot + atomic reduce ----
    float as[4], ad[4];
    #pragma unroll
    for (int nt = 0; nt < 4; ++nt) {
        as[nt] = avs[bn + nt * 16 + l15];
        ad[nt] = avd[bn + nt * 16 + l15];
    }

    #pragma unroll
    for (int mt = 0; mt < 2; ++mt) {
        int rbase = bm + wave * 32 + mt * 16 + quad * 4;
        #pragma unroll
        for (int nt = 0; nt < 4; ++nt) {
            int col = bn + nt * 16 + l15;
            #pragma unroll
            for (int r = 0; r < 4; ++r) {
                int row = rbase + r;
                if (row < N) H[(size_t)row * DFEAT + col] = f2bfbits(acc[mt][nt][r]);
            }
        }
        #pragma unroll
        for (int r = 0; r < 4; ++r) {
            float ps = acc[mt][0][r] * as[0] + acc[mt][1][r] * as[1]
                     + acc[mt][2][r] * as[2] + acc[mt][3][r] * as[3];
            float pd = acc[mt][0][r] * ad[0] + acc[mt][1][r] * ad[1]
                     + acc[mt][2][r] * ad[2] + acc[mt][3][r] * ad[3];
            #pragma unroll
            for (int m = 1; m < 16; m <<= 1) {
                ps += __shfl_xor(ps, m);
                pd += __shfl_xor(pd, m);
            }
            int row = rbase + r;
            if (l15 == 0 && row < N) {
                atomicAdd(&es[row], ps);
                atomicAdd(&ed[row], pd);
            }
        }
    }
}

// -------- aggregate, feature-sliced for L2 locality --------
// One WAVE per (node, slice): slice = 128 feats -> slice gather footprint
// N*4 lines = 2.56 MB < 4 MB per-XCD L2. Waves ordered slice-major, so the
// co-resident block window (~2k of 10k blocks) works ONE slice at a time on
// every XCD: random H gathers become local-L2 hits (~200cy) instead of LLC
// round-trips (~600cy). Lane owns 2 feats (4B load; 256B/wave-instr = 4 lines).
// Softmax preamble recomputed per slice (cheap: ~20 VALU + 40KB L2-hot es/ed).
__global__ __launch_bounds__(256) void aggregate_kernel(
    const unsigned short* __restrict__ H, const float* __restrict__ x,
    const float* __restrict__ bias,
    const int* __restrict__ cur, const int* __restrict__ slot,
    const float* __restrict__ es, const float* __restrict__ ed,
    float* __restrict__ out, int N)
{
    int gw   = blockIdx.x * 4 + (threadIdx.x >> 6);  // wave id, slice-major
    int lane = threadIdx.x & 63;
    if (gw >= NSLICE * N) return;
    int slice = 0, node = gw;
    if (node >= 2 * N) { slice = 2; node -= 2 * N; }
    if (node >= N)     { slice += 1; node -= N; }

    int k = cur[node];
    if (k > SLOTS) k = SLOTS;

    int   s = 0;
    float w = 0.f;
    if (lane < k) {
        s = slot[(size_t)node * SLOTS + lane];
        float e = es[s] + ed[node];
        e = e > 0.f ? e : 0.2f * e;            // leaky_relu
        w = __expf(e);                          // |e| small: no max-subtraction needed
    }
    float denom = w;
    #pragma unroll
    for (int off = 32; off > 0; off >>= 1) denom += __shfl_xor(denom, off);
    float inv = 1.0f / denom;

    float a0 = 0.f, a1 = 0.f;
    const char* Hb = (const char*)H + slice * (FS * 2) + lane * 4;  // 2 bf16/lane

    auto fma2 = [&](u32 hv, float wj) {
        a0 += wj * __uint_as_float(hv << 16);
        a1 += wj * __uint_as_float(hv & 0xffff0000u);
    };

    int j = 0;
    for (; j + 7 < k; j += 8) {                // 8 gathers in flight
        int   s0 = __shfl(s, j),     s1 = __shfl(s, j + 1);
        int   s2 = __shfl(s, j + 2), s3 = __shfl(s, j + 3);
        int   s4 = __shfl(s, j + 4), s5 = __shfl(s, j + 5);
        int   s6 = __shfl(s, j + 6), s7 = __shfl(s, j + 7);
        float w0 = __shfl(w, j),     w1 = __shfl(w, j + 1);
        float w2 = __shfl(w, j + 2), w3 = __shfl(w, j + 3);
        float w4 = __shfl(w, j + 4), w5 = __shfl(w, j + 5);
        float w6 = __shfl(w, j + 6), w7 = __shfl(w, j + 7);
        u32 h0 = *(const u32*)(Hb + (size_t)s0 * 1024);
        u32 h1 = *(const u32*)(Hb + (size_t)s1 * 1024);
        u32 h2 = *(const u32*)(Hb + (size_t)s2 * 1024);
        u32 h3 = *(const u32*)(Hb + (size_t)s3 * 1024);
        u32 h4 = *(const u32*)(Hb + (size_t)s4 * 1024);
        u32 h5 = *(const u32*)(Hb + (size_t)s5 * 1024);
        u32 h6 = *(const u32*)(Hb + (size_t)s6 * 1024);
        u32 h7 = *(const u32*)(Hb + (size_t)s7 * 1024);
        fma2(h0, w0); fma2(h1, w1); fma2(h2, w2); fma2(h3, w3);
        fma2(h4, w4); fma2(h5, w5); fma2(h6, w6); fma2(h7, w7);
    }
    if (j + 3 < k) {
        int   s0 = __shfl(s, j),     s1 = __shfl(s, j + 1);
        int   s2 = __shfl(s, j + 2), s3 = __shfl(s, j + 3);
        float w0 = __shfl(w, j),     w1 = __shfl(w, j + 1);
        float w2 = __shfl(w, j + 2), w3 = __shfl(w, j + 3);
        u32 h0 = *(const u32*)(Hb + (size_t)s0 * 1024);
        u32 h1 = *(const u32*)(Hb + (size_t)s1 * 1024);
        u32 h2 = *(const u32*)(Hb + (size_t)s2 * 1024);
        u32 h3 = *(const u32*)(Hb + (size_t)s3 * 1024);
        fma2(h0, w0); fma2(h1, w1); fma2(h2, w2); fma2(h3, w3);
        j += 4;
    }
    for (; j < k; ++j) {
        u32 hv = *(const u32*)(Hb + (size_t)__shfl(s, j) * 1024);
        fma2(hv, __shfl(w, j));
    }

    int c = slice * FS + lane * 2;
    float2 bv = *(const float2*)(bias + c);
    float2 xv = *(const float2*)(x + (size_t)node * DFEAT + c);
    float r0 = a0 * inv + bv.x;
    float r1 = a1 * inv + bv.y;
    r0 = r0 > 0.f ? r0 : __expf(r0) - 1.f;     // elu
    r1 = r1 > 0.f ? r1 : __expf(r1) - 1.f;
    float2 o = make_float2(xv.x + r0, xv.y + r1);
    *(float2*)(out + (size_t)node * DFEAT + c) = o;
}

extern "C" void kernel_launch(void* const* d_in, const int* in_sizes, int n_in,
                              void* d_out, int out_size, void* d_ws, size_t ws_size,
                              hipStream_t stream)
{
    const float* x    = (const float*)d_in[0];
    const int*   edge = (const int*)d_in[1];
    const float* Wm   = (const float*)d_in[2];
    const float* avs  = (const float*)d_in[3];
    const float* avd  = (const float*)d_in[4];
    const float* bias = (const float*)d_in[5];

    const int D = DFEAT;
    const int N = in_sizes[0] / D;
    const int E = in_sizes[1] / 2;
    const int T = E + N;
    const int* srcv = edge;
    const int* dstv = edge + E;

    char* ws = (char*)d_ws;
    size_t off = 0;
    auto alloc = [&](size_t bytes) -> char* {
        char* p = ws + off;
        off += (bytes + 255) & ~(size_t)255;
        return p;
    };
    // zero region: cur[N] | es[N] | ed[N]
    int*   cur  = (int*)alloc((size_t)N * 3 * 4);
    float* es   = (float*)(cur + N);
    float* ed   = es + N;
    int*   slot = (int*)alloc((size_t)N * SLOTS * 4);
    unsigned short* Xb = (unsigned short*)alloc((size_t)N * D * 2);
    unsigned short* Wb = (unsigned short*)alloc((size_t)D * D * 2);
    unsigned short* H  = (unsigned short*)alloc((size_t)N * D * 2);

    hipMemsetAsync(cur, 0, (size_t)N * 3 * 4, stream);

    int nx4   = (N * D) / 4;
    int ntot4 = nx4 + (D * D) / 4;
    int grid0 = (ntot4 > T ? ntot4 : T);
    cvt_scatter_kernel<<<dim3((grid0 + 255) / 256), 256, 0, stream>>>(
        x, Wm, Xb, Wb, srcv, dstv, cur, slot, nx4, ntot4, E, T);

    int rowPanels  = (N + 127) / 128;          // 128-row tiles
    int rowPanels8 = ((rowPanels + 7) / 8) * 8;
    gemm_h_kernel<<<dim3(rowPanels8 * 8), 256, 0, stream>>>(
        Xb, Wb, avs, avd, H, es, ed, N);

    int aggWaves = NSLICE * N;                 // one wave per (node, slice)
    aggregate_kernel<<<dim3((aggWaves * 64 + 255) / 256), 256, 0, stream>>>(
        H, x, bias, cur, slot, es, ed, (float*)d_out, N);
}